// Round 2
// baseline (455.414 us; speedup 1.0000x reference)
//
#include <hip/hip_runtime.h>

// Depthwise 3x3 conv, stride 1, pad 1, NCHW fp32 + bias.
// N=16, C=256, H=W=128. Memory-bound: 536.9 MB min traffic.
//
// Timed-graph decomposition (R0 rocprof): 2x harness re-poison fills
// (~336us, at HBM write ceiling, untouchable) + conv (~99us vs ~85us
// mixed-stream floor). This round targets the conv's last ~15%:
//
// R2b: (a) non-temporal float4 stores (via native ext_vector_type --
//     __builtin_nontemporal_store rejects HIP_vector_type structs);
//     output is write-once, keep the 256 MiB store stream out of the
//     4 MiB/XCD L2 so it can't evict input halo lines. (b) one block
//     per (n,c) plane looping over the 4 row-tiles -- inter-tile halo
//     rows become same-CU L1/L2 hits instead of cross-XCD re-fetches,
//     and weight/bias scalar loads amortize 4x. Input loads stay
//     cached (NOT non-temporal): halo reuse relies on L1/L2.

typedef float f32x4 __attribute__((ext_vector_type(4)));

constexpr int N_ = 16;
constexpr int C_ = 256;
constexpr int H_ = 128;
constexpr int W_ = 128;
constexpr int ROWS_PER_THREAD = 4;
constexpr int TY_PER_BLOCK = 8;                                  // 256 threads = 32 lanes x 8
constexpr int ROWS_PER_TILE = ROWS_PER_THREAD * TY_PER_BLOCK;    // 32
constexpr int TILES_PER_PLANE = H_ / ROWS_PER_TILE;              // 4

__global__ __launch_bounds__(256) void dwconv3x3_kernel(
    const float* __restrict__ x,
    const float* __restrict__ weight,   // (C,1,3,3)
    const float* __restrict__ bias,     // (C,)
    float* __restrict__ out) {

    const int lane = threadIdx.x & 31;    // 32 lanes -> 128 cols (float4 each)
    const int ty   = threadIdx.x >> 5;

    const int nc = blockIdx.x;            // one block per (n,c) plane
    const int c  = nc & (C_ - 1);

    const int w0 = lane * 4;

    const float* __restrict__ xp = x + (size_t)nc * (H_ * W_);
    float* __restrict__ op = out + (size_t)nc * (H_ * W_);

    // Channel-uniform weights/bias -> scalar broadcast loads, once per plane.
    const float* wp = weight + c * 9;
    float wgt[3][3];
#pragma unroll
    for (int k = 0; k < 3; ++k) {
#pragma unroll
        for (int j = 0; j < 3; ++j) wgt[k][j] = wp[k * 3 + j];
    }
    const float b = bias[c];

    for (int tile = 0; tile < TILES_PER_PLANE; ++tile) {
        const int h0 = tile * ROWS_PER_TILE + ty * ROWS_PER_THREAD;  // first output row

        // Issue all 6 input-row loads up front (independent, coalesced float4).
        float4 rows[6];
#pragma unroll
        for (int i = 0; i < 6; ++i) {
            const int r = h0 - 1 + i;
            if (r >= 0 && r < H_) {
                rows[i] = *(const float4*)(xp + r * W_ + w0);
            } else {
                rows[i] = make_float4(0.f, 0.f, 0.f, 0.f);
            }
        }

        float acc[ROWS_PER_THREAD][4];
#pragma unroll
        for (int o = 0; o < ROWS_PER_THREAD; ++o)
#pragma unroll
            for (int j = 0; j < 4; ++j) acc[o][j] = b;

        // Input row i (abs row h0-1+i) feeds output rows o = i-2..i with
        // weight row k = i - o. Column halo from neighbor lanes via shfl
        // (width 32: one subgroup == one full 128-wide image row).
#pragma unroll
        for (int i = 0; i < 6; ++i) {
            float e0 = __shfl_up(rows[i].w, 1, 32);
            if (lane == 0) e0 = 0.f;                 // image left edge
            float e5 = __shfl_down(rows[i].x, 1, 32);
            if (lane == 31) e5 = 0.f;                // image right edge
            const float e[6] = {e0, rows[i].x, rows[i].y, rows[i].z, rows[i].w, e5};

            const int olo = (i >= 2) ? (i - 2) : 0;
            const int ohi = (i < ROWS_PER_THREAD) ? i : (ROWS_PER_THREAD - 1);
#pragma unroll
            for (int o = olo; o <= ohi; ++o) {
                const int k = i - o;  // weight row, compile-time after unroll
#pragma unroll
                for (int j = 0; j < 4; ++j) {
                    float s = acc[o][j];
                    s = fmaf(wgt[k][0], e[j],     s);
                    s = fmaf(wgt[k][1], e[j + 1], s);
                    s = fmaf(wgt[k][2], e[j + 2], s);
                    acc[o][j] = s;
                }
            }
        }

#pragma unroll
        for (int o = 0; o < ROWS_PER_THREAD; ++o) {
            f32x4 ov;
            ov.x = acc[o][0]; ov.y = acc[o][1]; ov.z = acc[o][2]; ov.w = acc[o][3];
            // Write-once stream: bypass L2 allocation (nt) so the store
            // stream doesn't evict input halo lines.
            __builtin_nontemporal_store(ov, (f32x4*)(op + (h0 + o) * W_ + w0));
        }
    }
}

extern "C" void kernel_launch(void* const* d_in, const int* in_sizes, int n_in,
                              void* d_out, int out_size, void* d_ws, size_t ws_size,
                              hipStream_t stream) {
    const float* x      = (const float*)d_in[0];
    const float* weight = (const float*)d_in[1];
    const float* bias   = (const float*)d_in[2];
    float* out          = (float*)d_out;

    const int grid = N_ * C_;  // 4096 blocks, one per (n,c) plane, 16/CU
    dwconv3x3_kernel<<<grid, 256, 0, stream>>>(x, weight, bias, out);
}

// Round 3
// 444.693 us; speedup vs baseline: 1.0241x; 1.0241x over previous
//
#include <hip/hip_runtime.h>

// Depthwise 3x3 conv, stride 1, pad 1, NCHW fp32 + bias.
// N=16, C=256, H=W=128. Memory-bound: ~537 MB min traffic.
//
// R3: exact R0 structure (16384 blocks, one 32-row tile per block --
// known-good 433-435us; R2b's plane-loop regressed 20us by serializing
// tile loads behind store drains). SINGLE change vs R0: non-temporal
// float4 stores (native ext_vector_type; HIP_vector_type rejected by
// the builtin). Output is write-once -- keep the 256 MiB store stream
// from allocating in the 4 MiB/XCD L2 so input halo lines survive.

typedef float f32x4 __attribute__((ext_vector_type(4)));

constexpr int N_ = 16;
constexpr int C_ = 256;
constexpr int H_ = 128;
constexpr int W_ = 128;
constexpr int ROWS_PER_THREAD = 4;
constexpr int TY_PER_BLOCK = 8;                         // 256 threads = 32 lanes x 8
constexpr int ROWS_PER_BLOCK = ROWS_PER_THREAD * TY_PER_BLOCK;   // 32
constexpr int TILES_PER_PLANE = H_ / ROWS_PER_BLOCK;    // 4

__global__ __launch_bounds__(256) void dwconv3x3_kernel(
    const float* __restrict__ x,
    const float* __restrict__ weight,   // (C,1,3,3)
    const float* __restrict__ bias,     // (C,)
    float* __restrict__ out) {

    const int lane = threadIdx.x & 31;    // 32 lanes -> 128 cols (float4 each)
    const int ty   = threadIdx.x >> 5;

    const int bid  = blockIdx.x;
    const int tile = bid & (TILES_PER_PLANE - 1);
    const int nc   = bid >> 2;            // n*C + c, uniform per block
    const int c    = nc & (C_ - 1);

    const int h0 = tile * ROWS_PER_BLOCK + ty * ROWS_PER_THREAD;  // first output row
    const int w0 = lane * 4;

    const float* __restrict__ xp = x + (size_t)nc * (H_ * W_);
    float* __restrict__ op = out + (size_t)nc * (H_ * W_);

    // Channel-uniform weights/bias -> scalar broadcast loads.
    const float* wp = weight + c * 9;
    float wgt[3][3];
#pragma unroll
    for (int k = 0; k < 3; ++k) {
#pragma unroll
        for (int j = 0; j < 3; ++j) wgt[k][j] = wp[k * 3 + j];
    }
    const float b = bias[c];

    // Issue all 6 input-row loads up front (independent, coalesced float4).
    float4 rows[6];
#pragma unroll
    for (int i = 0; i < 6; ++i) {
        const int r = h0 - 1 + i;
        if (r >= 0 && r < H_) {
            rows[i] = *(const float4*)(xp + r * W_ + w0);
        } else {
            rows[i] = make_float4(0.f, 0.f, 0.f, 0.f);
        }
    }

    float acc[ROWS_PER_THREAD][4];
#pragma unroll
    for (int o = 0; o < ROWS_PER_THREAD; ++o)
#pragma unroll
        for (int j = 0; j < 4; ++j) acc[o][j] = b;

    // Input row i (abs row h0-1+i) feeds output rows o = i-2..i with weight
    // row k = i - o. Column halo from neighbor lanes via shfl (width 32: one
    // subgroup == one full 128-wide image row).
#pragma unroll
    for (int i = 0; i < 6; ++i) {
        float e0 = __shfl_up(rows[i].w, 1, 32);
        if (lane == 0) e0 = 0.f;                 // image left edge
        float e5 = __shfl_down(rows[i].x, 1, 32);
        if (lane == 31) e5 = 0.f;                // image right edge
        const float e[6] = {e0, rows[i].x, rows[i].y, rows[i].z, rows[i].w, e5};

        const int olo = (i >= 2) ? (i - 2) : 0;
        const int ohi = (i < ROWS_PER_THREAD) ? i : (ROWS_PER_THREAD - 1);
#pragma unroll
        for (int o = olo; o <= ohi; ++o) {
            const int k = i - o;  // weight row, compile-time after unroll
#pragma unroll
            for (int j = 0; j < 4; ++j) {
                float s = acc[o][j];
                s = fmaf(wgt[k][0], e[j],     s);
                s = fmaf(wgt[k][1], e[j + 1], s);
                s = fmaf(wgt[k][2], e[j + 2], s);
                acc[o][j] = s;
            }
        }
    }

#pragma unroll
    for (int o = 0; o < ROWS_PER_THREAD; ++o) {
        f32x4 ov;
        ov.x = acc[o][0]; ov.y = acc[o][1]; ov.z = acc[o][2]; ov.w = acc[o][3];
        // Write-once stream: non-temporal hint keeps stores from
        // evicting input halo lines in L2.
        __builtin_nontemporal_store(ov, (f32x4*)(op + (h0 + o) * W_ + w0));
    }
}

extern "C" void kernel_launch(void* const* d_in, const int* in_sizes, int n_in,
                              void* d_out, int out_size, void* d_ws, size_t ws_size,
                              hipStream_t stream) {
    const float* x      = (const float*)d_in[0];
    const float* weight = (const float*)d_in[1];
    const float* bias   = (const float*)d_in[2];
    float* out          = (float*)d_out;

    const int grid = N_ * C_ * TILES_PER_PLANE;  // 16384 blocks
    dwconv3x3_kernel<<<grid, 256, 0, stream>>>(x, weight, bias, out);
}

// Round 4
// 436.239 us; speedup vs baseline: 1.0440x; 1.0194x over previous
//
#include <hip/hip_runtime.h>

// Depthwise 3x3 conv, stride 1, pad 1, NCHW fp32 + bias.
// N=16, C=256, H=W=128. Memory-bound: ~537 MB min traffic.
//
// R4: exact R0 structure + data path (normal float4 stores -- R3 proved
// non-temporal stores REGRESS ~10us on gfx950: nt bypasses L2 write
// buffering and slows the store drain). SINGLE change vs R0: XCD-chunked
// blockIdx swizzle. Physical block b runs on XCD b%8; logical id
// swz=(b%8)*2048+b/8 gives each XCD a contiguous range of logical ids,
// so all 4 row-tiles of a plane land on ONE XCD's L2 and the inter-tile
// halo rows (~5% of reads) become L2 hits instead of HBM re-fetches.
// Bijective since 16384 % 8 == 0.

constexpr int N_ = 16;
constexpr int C_ = 256;
constexpr int H_ = 128;
constexpr int W_ = 128;
constexpr int ROWS_PER_THREAD = 4;
constexpr int TY_PER_BLOCK = 8;                         // 256 threads = 32 lanes x 8
constexpr int ROWS_PER_BLOCK = ROWS_PER_THREAD * TY_PER_BLOCK;   // 32
constexpr int TILES_PER_PLANE = H_ / ROWS_PER_BLOCK;    // 4
constexpr int NXCD = 8;
constexpr int GRID = N_ * C_ * TILES_PER_PLANE;         // 16384
constexpr int CPX  = GRID / NXCD;                       // 2048

__global__ __launch_bounds__(256) void dwconv3x3_kernel(
    const float* __restrict__ x,
    const float* __restrict__ weight,   // (C,1,3,3)
    const float* __restrict__ bias,     // (C,)
    float* __restrict__ out) {

    const int lane = threadIdx.x & 31;    // 32 lanes -> 128 cols (float4 each)
    const int ty   = threadIdx.x >> 5;

    // XCD-chunked swizzle: physical bid b -> XCD b%8 (round-robin HW
    // dispatch); remap so each XCD owns a contiguous logical range.
    const int bid  = (blockIdx.x & (NXCD - 1)) * CPX + (blockIdx.x >> 3);
    const int tile = bid & (TILES_PER_PLANE - 1);
    const int nc   = bid >> 2;            // n*C + c, uniform per block
    const int c    = nc & (C_ - 1);

    const int h0 = tile * ROWS_PER_BLOCK + ty * ROWS_PER_THREAD;  // first output row
    const int w0 = lane * 4;

    const float* __restrict__ xp = x + (size_t)nc * (H_ * W_);
    float* __restrict__ op = out + (size_t)nc * (H_ * W_);

    // Channel-uniform weights/bias -> scalar broadcast loads.
    const float* wp = weight + c * 9;
    float wgt[3][3];
#pragma unroll
    for (int k = 0; k < 3; ++k) {
#pragma unroll
        for (int j = 0; j < 3; ++j) wgt[k][j] = wp[k * 3 + j];
    }
    const float b = bias[c];

    // Issue all 6 input-row loads up front (independent, coalesced float4).
    float4 rows[6];
#pragma unroll
    for (int i = 0; i < 6; ++i) {
        const int r = h0 - 1 + i;
        if (r >= 0 && r < H_) {
            rows[i] = *(const float4*)(xp + r * W_ + w0);
        } else {
            rows[i] = make_float4(0.f, 0.f, 0.f, 0.f);
        }
    }

    float acc[ROWS_PER_THREAD][4];
#pragma unroll
    for (int o = 0; o < ROWS_PER_THREAD; ++o)
#pragma unroll
        for (int j = 0; j < 4; ++j) acc[o][j] = b;

    // Input row i (abs row h0-1+i) feeds output rows o = i-2..i with weight
    // row k = i - o. Column halo from neighbor lanes via shfl (width 32: one
    // subgroup == one full 128-wide image row).
#pragma unroll
    for (int i = 0; i < 6; ++i) {
        float e0 = __shfl_up(rows[i].w, 1, 32);
        if (lane == 0) e0 = 0.f;                 // image left edge
        float e5 = __shfl_down(rows[i].x, 1, 32);
        if (lane == 31) e5 = 0.f;                // image right edge
        const float e[6] = {e0, rows[i].x, rows[i].y, rows[i].z, rows[i].w, e5};

        const int olo = (i >= 2) ? (i - 2) : 0;
        const int ohi = (i < ROWS_PER_THREAD) ? i : (ROWS_PER_THREAD - 1);
#pragma unroll
        for (int o = olo; o <= ohi; ++o) {
            const int k = i - o;  // weight row, compile-time after unroll
#pragma unroll
            for (int j = 0; j < 4; ++j) {
                float s = acc[o][j];
                s = fmaf(wgt[k][0], e[j],     s);
                s = fmaf(wgt[k][1], e[j + 1], s);
                s = fmaf(wgt[k][2], e[j + 2], s);
                acc[o][j] = s;
            }
        }
    }

#pragma unroll
    for (int o = 0; o < ROWS_PER_THREAD; ++o) {
        float4 ov;
        ov.x = acc[o][0]; ov.y = acc[o][1]; ov.z = acc[o][2]; ov.w = acc[o][3];
        *(float4*)(op + (h0 + o) * W_ + w0) = ov;
    }
}

extern "C" void kernel_launch(void* const* d_in, const int* in_sizes, int n_in,
                              void* d_out, int out_size, void* d_ws, size_t ws_size,
                              hipStream_t stream) {
    const float* x      = (const float*)d_in[0];
    const float* weight = (const float*)d_in[1];
    const float* bias   = (const float*)d_in[2];
    float* out          = (float*)d_out;

    dwconv3x3_kernel<<<GRID, 256, 0, stream>>>(x, weight, bias, out);
}